// Round 1
// baseline (594.217 us; speedup 1.0000x reference)
//
#include <hip/hip_runtime.h>

typedef __attribute__((ext_vector_type(8))) short short8;
typedef __attribute__((ext_vector_type(4))) short bfx4;
typedef __attribute__((ext_vector_type(4))) float floatx4;

__device__ __forceinline__ float bf2f(short u) {
  unsigned int i = ((unsigned int)(unsigned short)u) << 16;
  return __builtin_bit_cast(float, i);
}
__device__ __forceinline__ short f2bf(float f) {
  unsigned int x = __builtin_bit_cast(unsigned int, f);
  x += 0x7fffu + ((x >> 16) & 1u);
  return (short)(x >> 16);
}

// async global->LDS, 16B per lane. LDS dest = wave-uniform base + lane*16.
__device__ __forceinline__ void gl_lds16(const short* g, short* lds) {
  __builtin_amdgcn_global_load_lds(
      (const __attribute__((address_space(1))) unsigned int*)g,
      (__attribute__((address_space(3))) unsigned int*)lds, 16, 0, 0);
}

#define BC 256  // batch chunk

// ---- gather: x[B,6400,2] f32 -> hA[64][BC][224] bf16 (K padded 200->224) -----
__global__ __launch_bounds__(256) void gather_x(const float* __restrict__ x,
                                                short* __restrict__ hA, int bOffset) {
  int tid = blockIdx.x * 256 + threadIdx.x;
  const int total = 64 * BC * 224;
  if (tid >= total) return;
  int kp = tid % 224;
  int rem = tid / 224;
  int b_loc = rem & (BC - 1);
  int j1 = rem / BC;
  short v = 0;
  if (kp < 200) {
    int c = kp & 1;
    int w = kp >> 1;
    int wx = w / 10;
    int wy = w - wx * 10;
    int bx = j1 >> 3, by = j1 & 7;
    v = f2bf(x[(size_t)(bOffset + b_loc) * 12800 +
               ((size_t)(bx * 800 + wx * 80 + by * 10 + wy)) * 2 + c]);
  }
  hA[tid] = v;
}

// ---- k1[64][200][1024] f32 -> k1t[64][1024][224] bf16 (B^T, zero-padded) -----
__global__ __launch_bounds__(256) void transpose_k1(const float* __restrict__ k1,
                                                    short* __restrict__ k1t) {
  const int j1 = blockIdx.x;          // 64
  const int nBase = blockIdx.y * 64;  // 16
  const int kBase = blockIdx.z * 56;  // 4
  __shared__ short tr[64][68];        // stride 136 B: 8B-aligned, 4-way-max banks
  const int t = threadIdx.x;
  const int nl = t & 63;
  const int ksub = t >> 6;
  const float* src = k1 + (size_t)j1 * 204800 + (size_t)kBase * 1024 + nBase + nl;
#pragma unroll
  for (int pass = 0; pass < 14; ++pass) {
    int kloc = pass * 4 + ksub;
    int k = kBase + kloc;
    tr[nl][kloc] = (k < 200) ? f2bf(src[kloc * 1024]) : (short)0;
  }
  __syncthreads();
  short* dstbase = k1t + ((size_t)j1 * 1024 + nBase) * 224 + kBase;
#pragma unroll
  for (int p = 0; p < 4; ++p) {
    int u = p * 256 + t;
    int row = u >> 4;
    int kq = u & 15;
    if (kq < 14) {
      bfx4 v = *(const bfx4*)&tr[row][kq * 4];
      *(bfx4*)&dstbase[row * 224 + kq * 4] = v;
    }
  }
}

// ---- k3[64][1024][200] f32 -> k3t[64][256][1024] bf16 (B^T, N padded) --------
__global__ __launch_bounds__(256) void transpose_k3(const float* __restrict__ k3,
                                                    short* __restrict__ k3t) {
  const int j3 = blockIdx.x;           // 64
  const int kBase = blockIdx.y * 128;  // 8
  const int nBase = blockIdx.z * 64;   // 4
  __shared__ short tr[64][132];
  const int t = threadIdx.x;
  const int nl = t & 63;
  const int ksub = t >> 6;
  const int nGlob = nBase + nl;
  const bool valid = (nGlob < 200);
  const float* src = k3 + (size_t)j3 * 204800 + (size_t)kBase * 200 + nGlob;
#pragma unroll 4
  for (int pass = 0; pass < 32; ++pass) {
    int k = pass * 4 + ksub;
    tr[nl][k] = valid ? f2bf(src[k * 200]) : (short)0;
  }
  __syncthreads();
  short* dstbase = k3t + ((size_t)j3 * 256 + nBase) * 1024 + kBase;
#pragma unroll
  for (int pass = 0; pass < 8; ++pass) {
    int idx = (pass * 256 + t) * 4;
    int row = idx >> 7;
    int koff = idx & 127;
    bfx4 v = *(const bfx4*)&tr[row][koff];
    *(bfx4*)&dstbase[row * 1024 + koff] = v;
  }
}

// ---- stage 1: per j1, C[BC,1024] = A[BC,224] @ Bt[1024,224]^T + b1 -----------
// 128x128 tile, global_load_lds(16B), 4 waves x (64x64), BK=32.
// v2: XCD-swizzled block mapping (8 j1's per XCD -> panels L2-resident) +
//     2-phase prefetch double-buffer (one barrier per K-step, loads in flight
//     across the MFMA phase; next barrier's implicit vmcnt(0) drains them).
__global__ __launch_bounds__(256) void gemm_stage1(const short* __restrict__ hA,
                                                   const short* __restrict__ k1t,
                                                   const float* __restrict__ b1,
                                                   short* __restrict__ h1) {
  // grid = (8, 2, 64) -> 1024 blocks. linear id = x + 8y + 16z.
  int bid = (int)blockIdx.x + 8 * (int)blockIdx.y + 16 * (int)blockIdx.z;
  bid = ((bid & 7) << 7) | (bid >> 3);  // bijective: XCD k gets [128k,128k+128)
  const int nBase = (bid & 7) * 128;
  const int mBase = ((bid >> 3) & 1) * 128;
  const int j1 = bid >> 4;
  __shared__ short As[2][128 * 32];
  __shared__ short Bs[2][128 * 32];
  const int tid = threadIdx.x;
  const int lane = tid & 63;
  const int wave = tid >> 6;
  const int quad = lane >> 4;
  const int l16 = lane & 15;
  const int wm = wave >> 1, wn = wave & 1;
  const int ldRow = tid >> 2;
  const int ldCol = (tid & 3) * 8;
  const short* Aj = hA + (size_t)j1 * BC * 224 + (size_t)(mBase + ldRow) * 224 + ldCol;
  const short* Bj = k1t + (size_t)j1 * 1024 * 224 + (size_t)(nBase + ldRow) * 224 + ldCol;
  const int lo = tid * 8;
  floatx4 acc[4][4] = {};

  // prologue: stage K-step 0 into buffer 0
  gl_lds16(Aj, &As[0][lo]);
  gl_lds16(Aj + 64 * 224, &As[0][lo + 2048]);
  gl_lds16(Bj, &Bs[0][lo]);
  gl_lds16(Bj + 64 * 224, &Bs[0][lo + 2048]);
  int buf = 0;
  for (int kk = 0; kk < 224; kk += 32) {
    __syncthreads();  // implicit vmcnt(0)+lgkmcnt(0): cur buffer landed in all waves
    if (kk + 32 < 224) {
      const int nb = buf ^ 1;
      gl_lds16(Aj + kk + 32, &As[nb][lo]);
      gl_lds16(Aj + 64 * 224 + kk + 32, &As[nb][lo + 2048]);
      gl_lds16(Bj + kk + 32, &Bs[nb][lo]);
      gl_lds16(Bj + 64 * 224 + kk + 32, &Bs[nb][lo + 2048]);
    }
    short8 af[4], bfv[4];
#pragma unroll
    for (int mt = 0; mt < 4; ++mt)
      af[mt] = *(const short8*)&As[buf][(wm * 64 + mt * 16 + l16) * 32 + quad * 8];
#pragma unroll
    for (int nt = 0; nt < 4; ++nt)
      bfv[nt] = *(const short8*)&Bs[buf][(wn * 64 + nt * 16 + l16) * 32 + quad * 8];
#pragma unroll
    for (int mt = 0; mt < 4; ++mt)
#pragma unroll
      for (int nt = 0; nt < 4; ++nt)
        acc[mt][nt] =
            __builtin_amdgcn_mfma_f32_16x16x32_bf16(af[mt], bfv[nt], acc[mt][nt], 0, 0, 0);
    buf ^= 1;
  }
#pragma unroll
  for (int nt = 0; nt < 4; ++nt) {
    int n = nBase + wn * 64 + nt * 16 + l16;
    float bias = b1[j1 * 1024 + n];
#pragma unroll
    for (int mt = 0; mt < 4; ++mt) {
#pragma unroll
      for (int r = 0; r < 4; ++r) {
        int m = mBase + wm * 64 + mt * 16 + quad * 4 + r;
        h1[((size_t)j1 * BC + m) * 1024 + n] = f2bf(acc[mt][nt][r] + bias);
      }
    }
  }
}

// ---- stage 2: permute + tiny GEMMs, h1[64][BC][1024] -> h2p[64][mTot][1024] --
__global__ __launch_bounds__(256) void stage2(const short* __restrict__ h1,
                                              const float* __restrict__ k2,
                                              const float* __restrict__ b2,
                                              short* __restrict__ h2p, int mTot,
                                              int bOff2) {
  const int j1 = blockIdx.x;
  const int bBase = blockIdx.y * 8;
  __shared__ short in_s[8][1024];
  __shared__ short w_s[256 * 66];
  __shared__ float bias_s[16 * 64];
  const int tid = threadIdx.x;
#pragma unroll
  for (int ii = 0; ii < 4; ++ii) {
    int flat = (ii * 256 + tid) * 8;
    int b_loc = flat >> 10;
    int k = flat & 1023;
    *(short8*)&in_s[b_loc][k] =
        *(const short8*)&h1[((size_t)j1 * BC + bBase + b_loc) * 1024 + k];
  }
#pragma unroll
  for (int ii = 0; ii < 16; ++ii) {
    int flat = (ii * 256 + tid) * 4;
    int blk = flat >> 8;
    int within = flat & 255;
    int r = blk >> 2, b2hi = blk & 3;
    int j2 = r * 256 + j1 * 4 + b2hi;
    floatx4 v = *(const floatx4*)&k2[(size_t)j2 * 256 + within];
#pragma unroll
    for (int i = 0; i < 4; ++i) w_s[(within + i) * 66 + blk] = f2bf(v[i]);
  }
  {
    int blk = tid >> 2;
    int r2o = (tid & 3) * 4;
    int r = blk >> 2, b2hi = blk & 3;
    int j2 = r * 256 + j1 * 4 + b2hi;
#pragma unroll
    for (int i = 0; i < 4; ++i) bias_s[(r2o + i) * 64 + blk] = b2[j2 * 16 + r2o + i];
  }
  __syncthreads();
#pragma unroll
  for (int i4 = 0; i4 < 2; ++i4) {
    int idx = i4 * 256 + tid;
    int b_loc = idx >> 6;
    int rem = idx & 63;
    int r = rem >> 2;
    int b2hi = rem & 3;
    float acc[16];
#pragma unroll
    for (int r2 = 0; r2 < 16; ++r2) acc[r2] = bias_s[r2 * 64 + rem];
#pragma unroll
    for (int k = 0; k < 16; ++k) {
      float iv = bf2f(in_s[b_loc][(b2hi * 16 + k) * 16 + r]);
#pragma unroll
      for (int r2 = 0; r2 < 16; ++r2)
        acc[r2] += iv * bf2f(w_s[(k * 16 + r2) * 66 + rem]);
    }
    int j3 = r * 4 + (j1 >> 4);
    int k3o = (j1 & 15) * 64 + b2hi * 16;
    short8 o0, o1;
#pragma unroll
    for (int t = 0; t < 8; ++t) {
      o0[t] = f2bf(acc[t]);
      o1[t] = f2bf(acc[8 + t]);
    }
    short* dst = h2p + ((size_t)j3 * mTot + bOff2 + bBase + b_loc) * 1024 + k3o;
    *(short8*)&dst[0] = o0;
    *(short8*)&dst[8] = o1;
  }
}

// ---- stage 3: per j3, [M,1024] @ k3t^T (+b3), scatter to out f32 -------------
// v2: XCD-swizzled block mapping + 2-phase prefetch double-buffer (see stage1).
__global__ __launch_bounds__(256) void gemm_stage3(const short* __restrict__ h2p,
                                                   const short* __restrict__ k3t,
                                                   const float* __restrict__ b3,
                                                   float* __restrict__ out, int mTot,
                                                   int bOffset) {
  // grid = (2, mTot/128, 64); mTot/128 is 2 or 8 (both pow2), nwg % 8 == 0.
  const int gy = (int)gridDim.y;
  int bid = (int)blockIdx.x + 2 * ((int)blockIdx.y + gy * (int)blockIdx.z);
  const int cpx = (gy << 4);  // nwg/8 = 2*gy*64/8
  bid = (bid & 7) * cpx + (bid >> 3);
  const int nBase = (bid & 1) * 128;
  const int rest = bid >> 1;
  const int mBase = (rest & (gy - 1)) * 128;
  const int j3 = rest / gy;
  __shared__ short As[2][128 * 32];
  __shared__ short Bs[2][128 * 32];
  const int tid = threadIdx.x;
  const int lane = tid & 63;
  const int wave = tid >> 6;
  const int quad = lane >> 4;
  const int l16 = lane & 15;
  const int wm = wave >> 1, wn = wave & 1;
  const int ldRow = tid >> 2;
  const int ldCol = (tid & 3) * 8;
  const short* Aj =
      h2p + (size_t)j3 * mTot * 1024 + (size_t)(mBase + ldRow) * 1024 + ldCol;
  const short* Bj =
      k3t + (size_t)j3 * 256 * 1024 + (size_t)(nBase + ldRow) * 1024 + ldCol;
  const int lo = tid * 8;
  floatx4 acc[4][4] = {};

  // prologue: stage K-step 0 into buffer 0
  gl_lds16(Aj, &As[0][lo]);
  gl_lds16(Aj + 64 * 1024, &As[0][lo + 2048]);
  gl_lds16(Bj, &Bs[0][lo]);
  gl_lds16(Bj + 64 * 1024, &Bs[0][lo + 2048]);
  int buf = 0;
  for (int kk = 0; kk < 1024; kk += 32) {
    __syncthreads();  // implicit vmcnt(0)+lgkmcnt(0): cur buffer landed in all waves
    if (kk + 32 < 1024) {
      const int nb = buf ^ 1;
      gl_lds16(Aj + kk + 32, &As[nb][lo]);
      gl_lds16(Aj + 64 * 1024 + kk + 32, &As[nb][lo + 2048]);
      gl_lds16(Bj + kk + 32, &Bs[nb][lo]);
      gl_lds16(Bj + 64 * 1024 + kk + 32, &Bs[nb][lo + 2048]);
    }
    short8 af[4], bfv[4];
#pragma unroll
    for (int mt = 0; mt < 4; ++mt)
      af[mt] = *(const short8*)&As[buf][(wm * 64 + mt * 16 + l16) * 32 + quad * 8];
#pragma unroll
    for (int nt = 0; nt < 4; ++nt)
      bfv[nt] = *(const short8*)&Bs[buf][(wn * 64 + nt * 16 + l16) * 32 + quad * 8];
#pragma unroll
    for (int mt = 0; mt < 4; ++mt)
#pragma unroll
      for (int nt = 0; nt < 4; ++nt)
        acc[mt][nt] =
            __builtin_amdgcn_mfma_f32_16x16x32_bf16(af[mt], bfv[nt], acc[mt][nt], 0, 0, 0);
    buf ^= 1;
  }
  const int B2x = j3 >> 3, B2y = j3 & 7;
#pragma unroll
  for (int nt = 0; nt < 4; ++nt) {
    int n = nBase + wn * 64 + nt * 16 + l16;
    if (n < 200) {
      float bias = b3[j3 * 200 + n];
      int c = n & 1;
      int t = n >> 1;
      int w2x = t / 10, w2y = t - w2x * 10;
      int orow = B2x * 10 + w2x, ocol = B2y * 10 + w2y;
#pragma unroll
      for (int mt = 0; mt < 4; ++mt) {
#pragma unroll
        for (int r = 0; r < 4; ++r) {
          int m = bOffset + mBase + wm * 64 + mt * 16 + quad * 4 + r;
          out[(((size_t)m * 80 + orow) * 80 + ocol) * 2 + c] = acc[mt][nt][r] + bias;
        }
      }
    }
  }
}

extern "C" void kernel_launch(void* const* d_in, const int* in_sizes, int n_in,
                              void* d_out, int out_size, void* d_ws, size_t ws_size,
                              hipStream_t stream) {
  const float* x = (const float*)d_in[0];
  const float* k1 = (const float*)d_in[1];
  const float* b1 = (const float*)d_in[2];
  const float* k2 = (const float*)d_in[3];
  const float* b2 = (const float*)d_in[4];
  const float* k3 = (const float*)d_in[5];
  const float* b3 = (const float*)d_in[6];
  float* out = (float*)d_out;
  char* ws = (char*)d_ws;

  short* k1t = (short*)(ws);                // 29,360,128
  short* k3t = (short*)(ws + 29360128);     // 33,554,432
  short* hA = (short*)(ws + 62914560);      //  7,340,032
  short* h1c = (short*)(ws + 70254592);     // 33,554,432
  short* h2p = (short*)(ws + 103809024);    // 33,554,432 (chunked) / 134,217,728 (full)

  const bool full = (ws_size >= 238026752ull);  // full h2p fits
  const int mTot = full ? 1024 : BC;

  transpose_k1<<<dim3(64, 16, 4), 256, 0, stream>>>(k1, k1t);
  transpose_k3<<<dim3(64, 8, 4), 256, 0, stream>>>(k3, k3t);
  for (int c = 0; c < 1024 / BC; ++c) {
    int bOffset = c * BC;
    gather_x<<<(64 * BC * 224) / 256, 256, 0, stream>>>(x, hA, bOffset);
    gemm_stage1<<<dim3(8, BC / 128, 64), 256, 0, stream>>>(hA, k1t, b1, h1c);
    stage2<<<dim3(64, BC / 8), 256, 0, stream>>>(h1c, k2, b2, h2p, mTot,
                                                 full ? bOffset : 0);
    if (!full)
      gemm_stage3<<<dim3(2, BC / 128, 64), 256, 0, stream>>>(h2p, k3t, b3, out, BC,
                                                             bOffset);
  }
  if (full)
    gemm_stage3<<<dim3(2, 1024 / 128, 64), 256, 0, stream>>>(h2p, k3t, b3, out, 1024,
                                                             0);
}

// Round 2
// 568.888 us; speedup vs baseline: 1.0445x; 1.0445x over previous
//
#include <hip/hip_runtime.h>

typedef __attribute__((ext_vector_type(8))) short short8;
typedef __attribute__((ext_vector_type(4))) short bfx4;
typedef __attribute__((ext_vector_type(4))) float floatx4;

__device__ __forceinline__ float bf2f(short u) {
  unsigned int i = ((unsigned int)(unsigned short)u) << 16;
  return __builtin_bit_cast(float, i);
}
__device__ __forceinline__ short f2bf(float f) {
  unsigned int x = __builtin_bit_cast(unsigned int, f);
  x += 0x7fffu + ((x >> 16) & 1u);
  return (short)(x >> 16);
}

// async global->LDS, 16B per lane. LDS dest = wave-uniform base + lane*16.
__device__ __forceinline__ void gl_lds16(const short* g, short* lds) {
  __builtin_amdgcn_global_load_lds(
      (const __attribute__((address_space(1))) unsigned int*)g,
      (__attribute__((address_space(3))) unsigned int*)lds, 16, 0, 0);
}

#define BC 256  // batch chunk

// ---- gather: x[B,6400,2] f32 -> hA[64][BC][224] bf16 (K padded 200->224) -----
__global__ __launch_bounds__(256) void gather_x(const float* __restrict__ x,
                                                short* __restrict__ hA, int bOffset) {
  int tid = blockIdx.x * 256 + threadIdx.x;
  const int total = 64 * BC * 224;
  if (tid >= total) return;
  int kp = tid % 224;
  int rem = tid / 224;
  int b_loc = rem & (BC - 1);
  int j1 = rem / BC;
  short v = 0;
  if (kp < 200) {
    int c = kp & 1;
    int w = kp >> 1;
    int wx = w / 10;
    int wy = w - wx * 10;
    int bx = j1 >> 3, by = j1 & 7;
    v = f2bf(x[(size_t)(bOffset + b_loc) * 12800 +
               ((size_t)(bx * 800 + wx * 80 + by * 10 + wy)) * 2 + c]);
  }
  hA[tid] = v;
}

// ---- k1[64][200][1024] f32 -> k1t[64][1024][224] bf16 (B^T, zero-padded) -----
__global__ __launch_bounds__(256) void transpose_k1(const float* __restrict__ k1,
                                                    short* __restrict__ k1t) {
  const int j1 = blockIdx.x;          // 64
  const int nBase = blockIdx.y * 64;  // 16
  const int kBase = blockIdx.z * 56;  // 4
  __shared__ short tr[64][68];        // stride 136 B: 8B-aligned, 4-way-max banks
  const int t = threadIdx.x;
  const int nl = t & 63;
  const int ksub = t >> 6;
  const float* src = k1 + (size_t)j1 * 204800 + (size_t)kBase * 1024 + nBase + nl;
#pragma unroll
  for (int pass = 0; pass < 14; ++pass) {
    int kloc = pass * 4 + ksub;
    int k = kBase + kloc;
    tr[nl][kloc] = (k < 200) ? f2bf(src[kloc * 1024]) : (short)0;
  }
  __syncthreads();
  short* dstbase = k1t + ((size_t)j1 * 1024 + nBase) * 224 + kBase;
#pragma unroll
  for (int p = 0; p < 4; ++p) {
    int u = p * 256 + t;
    int row = u >> 4;
    int kq = u & 15;
    if (kq < 14) {
      bfx4 v = *(const bfx4*)&tr[row][kq * 4];
      *(bfx4*)&dstbase[row * 224 + kq * 4] = v;
    }
  }
}

// ---- k3[64][1024][200] f32 -> k3t[64][256][1024] bf16 (B^T, N padded) --------
__global__ __launch_bounds__(256) void transpose_k3(const float* __restrict__ k3,
                                                    short* __restrict__ k3t) {
  const int j3 = blockIdx.x;           // 64
  const int kBase = blockIdx.y * 128;  // 8
  const int nBase = blockIdx.z * 64;   // 4
  __shared__ short tr[64][132];
  const int t = threadIdx.x;
  const int nl = t & 63;
  const int ksub = t >> 6;
  const int nGlob = nBase + nl;
  const bool valid = (nGlob < 200);
  const float* src = k3 + (size_t)j3 * 204800 + (size_t)kBase * 200 + nGlob;
#pragma unroll 4
  for (int pass = 0; pass < 32; ++pass) {
    int k = pass * 4 + ksub;
    tr[nl][k] = valid ? f2bf(src[k * 200]) : (short)0;
  }
  __syncthreads();
  short* dstbase = k3t + ((size_t)j3 * 256 + nBase) * 1024 + kBase;
#pragma unroll
  for (int pass = 0; pass < 8; ++pass) {
    int idx = (pass * 256 + t) * 4;
    int row = idx >> 7;
    int koff = idx & 127;
    bfx4 v = *(const bfx4*)&tr[row][koff];
    *(bfx4*)&dstbase[row * 1024 + koff] = v;
  }
}

// ---- stage 1: per j1, C[BC,1024] = A[BC,224] @ Bt[1024,224]^T + b1 -----------
// m97-style: 128x128 tile, global_load_lds(16B), 4 waves x (64x64), BK=32.
// (round-0 verbatim: proven 2-barrier structure)
__global__ __launch_bounds__(256) void gemm_stage1(const short* __restrict__ hA,
                                                   const short* __restrict__ k1t,
                                                   const float* __restrict__ b1,
                                                   short* __restrict__ h1) {
  const int j1 = blockIdx.z;
  const int mBase = blockIdx.y * 128;
  const int nBase = blockIdx.x * 128;
  __shared__ short As[128 * 32];
  __shared__ short Bs[128 * 32];
  const int tid = threadIdx.x;
  const int lane = tid & 63;
  const int wave = tid >> 6;
  const int quad = lane >> 4;
  const int l16 = lane & 15;
  const int wm = wave >> 1, wn = wave & 1;
  const int ldRow = tid >> 2;
  const int ldCol = (tid & 3) * 8;
  const short* Aj = hA + (size_t)j1 * BC * 224 + (size_t)(mBase + ldRow) * 224 + ldCol;
  const short* Bj = k1t + (size_t)j1 * 1024 * 224 + (size_t)(nBase + ldRow) * 224 + ldCol;
  short* ldsA = &As[tid * 8];
  short* ldsB = &Bs[tid * 8];
  floatx4 acc[4][4] = {};

  for (int kk = 0; kk < 224; kk += 32) {
    __syncthreads();
    gl_lds16(Aj + kk, ldsA);
    gl_lds16(Aj + 64 * 224 + kk, ldsA + 64 * 32);
    gl_lds16(Bj + kk, ldsB);
    gl_lds16(Bj + 64 * 224 + kk, ldsB + 64 * 32);
    __syncthreads();
    short8 af[4], bf[4];
#pragma unroll
    for (int mt = 0; mt < 4; ++mt)
      af[mt] = *(const short8*)&As[(wm * 64 + mt * 16 + l16) * 32 + quad * 8];
#pragma unroll
    for (int nt = 0; nt < 4; ++nt)
      bf[nt] = *(const short8*)&Bs[(wn * 64 + nt * 16 + l16) * 32 + quad * 8];
#pragma unroll
    for (int mt = 0; mt < 4; ++mt)
#pragma unroll
      for (int nt = 0; nt < 4; ++nt)
        acc[mt][nt] =
            __builtin_amdgcn_mfma_f32_16x16x32_bf16(af[mt], bf[nt], acc[mt][nt], 0, 0, 0);
  }
#pragma unroll
  for (int nt = 0; nt < 4; ++nt) {
    int n = nBase + wn * 64 + nt * 16 + l16;
    float bias = b1[j1 * 1024 + n];
#pragma unroll
    for (int mt = 0; mt < 4; ++mt) {
#pragma unroll
      for (int r = 0; r < 4; ++r) {
        int m = mBase + wm * 64 + mt * 16 + quad * 4 + r;
        h1[((size_t)j1 * BC + m) * 1024 + n] = f2bf(acc[mt][nt][r] + bias);
      }
    }
  }
}

// ---- stage 2: permute + tiny GEMMs, h1[64][BC][1024] -> h2p[64][mTot][1024] --
__global__ __launch_bounds__(256) void stage2(const short* __restrict__ h1,
                                              const float* __restrict__ k2,
                                              const float* __restrict__ b2,
                                              short* __restrict__ h2p, int mTot,
                                              int bOff2) {
  const int j1 = blockIdx.x;
  const int bBase = blockIdx.y * 8;
  __shared__ short in_s[8][1024];
  __shared__ short w_s[256 * 66];
  __shared__ float bias_s[16 * 64];
  const int tid = threadIdx.x;
#pragma unroll
  for (int ii = 0; ii < 4; ++ii) {
    int flat = (ii * 256 + tid) * 8;
    int b_loc = flat >> 10;
    int k = flat & 1023;
    *(short8*)&in_s[b_loc][k] =
        *(const short8*)&h1[((size_t)j1 * BC + bBase + b_loc) * 1024 + k];
  }
#pragma unroll
  for (int ii = 0; ii < 16; ++ii) {
    int flat = (ii * 256 + tid) * 4;
    int blk = flat >> 8;
    int within = flat & 255;
    int r = blk >> 2, b2hi = blk & 3;
    int j2 = r * 256 + j1 * 4 + b2hi;
    floatx4 v = *(const floatx4*)&k2[(size_t)j2 * 256 + within];
#pragma unroll
    for (int i = 0; i < 4; ++i) w_s[(within + i) * 66 + blk] = f2bf(v[i]);
  }
  {
    int blk = tid >> 2;
    int r2o = (tid & 3) * 4;
    int r = blk >> 2, b2hi = blk & 3;
    int j2 = r * 256 + j1 * 4 + b2hi;
#pragma unroll
    for (int i = 0; i < 4; ++i) bias_s[(r2o + i) * 64 + blk] = b2[j2 * 16 + r2o + i];
  }
  __syncthreads();
#pragma unroll
  for (int i4 = 0; i4 < 2; ++i4) {
    int idx = i4 * 256 + tid;
    int b_loc = idx >> 6;
    int rem = idx & 63;
    int r = rem >> 2;
    int b2hi = rem & 3;
    float acc[16];
#pragma unroll
    for (int r2 = 0; r2 < 16; ++r2) acc[r2] = bias_s[r2 * 64 + rem];
#pragma unroll
    for (int k = 0; k < 16; ++k) {
      float iv = bf2f(in_s[b_loc][(b2hi * 16 + k) * 16 + r]);
#pragma unroll
      for (int r2 = 0; r2 < 16; ++r2)
        acc[r2] += iv * bf2f(w_s[(k * 16 + r2) * 66 + rem]);
    }
    int j3 = r * 4 + (j1 >> 4);
    int k3o = (j1 & 15) * 64 + b2hi * 16;
    short8 o0, o1;
#pragma unroll
    for (int t = 0; t < 8; ++t) {
      o0[t] = f2bf(acc[t]);
      o1[t] = f2bf(acc[8 + t]);
    }
    short* dst = h2p + ((size_t)j3 * mTot + bOff2 + bBase + b_loc) * 1024 + k3o;
    *(short8*)&dst[0] = o0;
    *(short8*)&dst[8] = o1;
  }
}

// ---- stage 3: per j3, [M,1024] @ k3t^T (+b3), scatter to out f32 -------------
// v3: proven 2-barrier structure, BK=64 (16 iters instead of 32 -> half the
// barrier/drain events), T2 XOR-swizzle rule-#21 style: linear LDS dest for
// global_load_lds, inverse-swizzled GLOBAL source (slot ^= row&7 within each
// row's 8x16B chunks; still coalesced per 128B row segment), same involution
// on the ds_read side. Post-swizzle reads: 2 lanes/bank = free.
// XCD-aware bijective block swizzle kept (halved FETCH_SIZE in round 1).
__global__ __launch_bounds__(256) void gemm_stage3(const short* __restrict__ h2p,
                                                   const short* __restrict__ k3t,
                                                   const float* __restrict__ b3,
                                                   float* __restrict__ out, int mTot,
                                                   int bOffset) {
  // grid = (2, mTot/128, 64); nwg % 8 == 0, swizzle is bijective.
  const int gy = (int)gridDim.y;
  int bid = (int)blockIdx.x + 2 * ((int)blockIdx.y + gy * (int)blockIdx.z);
  const int cpx = (gy << 4);  // nwg/8
  bid = (bid & 7) * cpx + (bid >> 3);
  const int nBase = (bid & 1) * 128;
  const int rest = bid >> 1;
  const int mBase = (rest & (gy - 1)) * 128;
  const int j3 = rest / gy;
  __shared__ short As[128 * 64];  // 16 KB, swizzled content
  __shared__ short Bs[128 * 64];  // 16 KB
  const int tid = threadIdx.x;
  const int lane = tid & 63;
  const int wave = tid >> 6;
  const int quad = lane >> 4;
  const int l16 = lane & 15;
  const int wm = wave >> 1, wn = wave & 1;
  // staging: call c covers rows [c*32, c*32+32); thread -> row = c*32 + (tid>>3),
  // phys 16B-slot = tid&7 which must hold logical slot (tid&7)^(row&7).
  const int sRow = tid >> 3;
  const int sCol = ((tid & 7) ^ (sRow & 7)) * 8;  // shorts; row&7 == sRow&7 for all c
  const short* Aj =
      h2p + (size_t)j3 * mTot * 1024 + (size_t)(mBase + sRow) * 1024 + sCol;
  const short* Bj =
      k3t + (size_t)j3 * 256 * 1024 + (size_t)(nBase + sRow) * 1024 + sCol;
  short* ldsA = &As[tid * 8];
  short* ldsB = &Bs[tid * 8];
  floatx4 acc[4][4] = {};

  for (int kk = 0; kk < 1024; kk += 64) {
    __syncthreads();
#pragma unroll
    for (int c = 0; c < 4; ++c) {
      gl_lds16(Aj + c * 32 * 1024 + kk, ldsA + c * 2048);
      gl_lds16(Bj + c * 32 * 1024 + kk, ldsB + c * 2048);
    }
    __syncthreads();
#pragma unroll
    for (int ks = 0; ks < 2; ++ks) {
      short8 af[4], bfv[4];
#pragma unroll
      for (int mt = 0; mt < 4; ++mt) {
        int r = wm * 64 + mt * 16 + l16;
        af[mt] = *(const short8*)&As[r * 64 + ((ks * 4 + quad) ^ (l16 & 7)) * 8];
      }
#pragma unroll
      for (int nt = 0; nt < 4; ++nt) {
        int r = wn * 64 + nt * 16 + l16;
        bfv[nt] = *(const short8*)&Bs[r * 64 + ((ks * 4 + quad) ^ (l16 & 7)) * 8];
      }
#pragma unroll
      for (int mt = 0; mt < 4; ++mt)
#pragma unroll
        for (int nt = 0; nt < 4; ++nt)
          acc[mt][nt] = __builtin_amdgcn_mfma_f32_16x16x32_bf16(af[mt], bfv[nt],
                                                                acc[mt][nt], 0, 0, 0);
    }
  }
  const int B2x = j3 >> 3, B2y = j3 & 7;
#pragma unroll
  for (int nt = 0; nt < 4; ++nt) {
    int n = nBase + wn * 64 + nt * 16 + l16;
    if (n < 200) {
      float bias = b3[j3 * 200 + n];
      int c = n & 1;
      int t = n >> 1;
      int w2x = t / 10, w2y = t - w2x * 10;
      int orow = B2x * 10 + w2x, ocol = B2y * 10 + w2y;
#pragma unroll
      for (int mt = 0; mt < 4; ++mt) {
#pragma unroll
        for (int r = 0; r < 4; ++r) {
          int m = bOffset + mBase + wm * 64 + mt * 16 + quad * 4 + r;
          out[(((size_t)m * 80 + orow) * 80 + ocol) * 2 + c] = acc[mt][nt][r] + bias;
        }
      }
    }
  }
}

extern "C" void kernel_launch(void* const* d_in, const int* in_sizes, int n_in,
                              void* d_out, int out_size, void* d_ws, size_t ws_size,
                              hipStream_t stream) {
  const float* x = (const float*)d_in[0];
  const float* k1 = (const float*)d_in[1];
  const float* b1 = (const float*)d_in[2];
  const float* k2 = (const float*)d_in[3];
  const float* b2 = (const float*)d_in[4];
  const float* k3 = (const float*)d_in[5];
  const float* b3 = (const float*)d_in[6];
  float* out = (float*)d_out;
  char* ws = (char*)d_ws;

  short* k1t = (short*)(ws);                // 29,360,128
  short* k3t = (short*)(ws + 29360128);     // 33,554,432
  short* hA = (short*)(ws + 62914560);      //  7,340,032
  short* h1c = (short*)(ws + 70254592);     // 33,554,432
  short* h2p = (short*)(ws + 103809024);    // 33,554,432 (chunked) / 134,217,728 (full)

  const bool full = (ws_size >= 238026752ull);  // full h2p fits
  const int mTot = full ? 1024 : BC;

  transpose_k1<<<dim3(64, 16, 4), 256, 0, stream>>>(k1, k1t);
  transpose_k3<<<dim3(64, 8, 4), 256, 0, stream>>>(k3, k3t);
  for (int c = 0; c < 1024 / BC; ++c) {
    int bOffset = c * BC;
    gather_x<<<(64 * BC * 224) / 256, 256, 0, stream>>>(x, hA, bOffset);
    gemm_stage1<<<dim3(8, BC / 128, 64), 256, 0, stream>>>(hA, k1t, b1, h1c);
    stage2<<<dim3(64, BC / 8), 256, 0, stream>>>(h1c, k2, b2, h2p, mTot,
                                                 full ? bOffset : 0);
    if (!full)
      gemm_stage3<<<dim3(2, BC / 128, 64), 256, 0, stream>>>(h2p, k3t, b3, out, BC,
                                                             bOffset);
  }
  if (full)
    gemm_stage3<<<dim3(2, 1024 / 128, 64), 256, 0, stream>>>(h2p, k3t, b3, out, 1024,
                                                             0);
}

// Round 3
// 534.228 us; speedup vs baseline: 1.1123x; 1.0649x over previous
//
#include <hip/hip_runtime.h>

typedef __attribute__((ext_vector_type(8))) short short8;
typedef __attribute__((ext_vector_type(4))) short bfx4;
typedef __attribute__((ext_vector_type(4))) float floatx4;

__device__ __forceinline__ float bf2f(short u) {
  unsigned int i = ((unsigned int)(unsigned short)u) << 16;
  return __builtin_bit_cast(float, i);
}
__device__ __forceinline__ short f2bf(float f) {
  unsigned int x = __builtin_bit_cast(unsigned int, f);
  x += 0x7fffu + ((x >> 16) & 1u);
  return (short)(x >> 16);
}

// async global->LDS, 16B per lane. LDS dest = wave-uniform base + lane*16.
__device__ __forceinline__ void gl_lds16(const short* g, short* lds) {
  __builtin_amdgcn_global_load_lds(
      (const __attribute__((address_space(1))) unsigned int*)g,
      (__attribute__((address_space(3))) unsigned int*)lds, 16, 0, 0);
}

#define BC 256  // batch chunk

// ---- gather: x[B,6400,2] f32 -> hA[64][BC][224] bf16 (K padded 200->224) -----
// v3: one c-pair per thread (float2 load, packed 4B store).
__global__ __launch_bounds__(256) void gather_x(const float* __restrict__ x,
                                                short* __restrict__ hA, int bOffset) {
  int tid = blockIdx.x * 256 + threadIdx.x;
  const int total = 64 * BC * 112;
  if (tid >= total) return;
  int kp2 = tid % 112;   // pair index: w = kp2, covers kp = 2*kp2, 2*kp2+1
  int rem = tid / 112;
  int b_loc = rem & (BC - 1);
  int j1 = rem / BC;
  unsigned int pair = 0;
  if (kp2 < 100) {
    int wx = kp2 / 10;
    int wy = kp2 - wx * 10;
    int bx = j1 >> 3, by = j1 & 7;
    const float* p = x + (size_t)(bOffset + b_loc) * 12800 +
                     ((size_t)(bx * 800 + wx * 80 + by * 10 + wy)) * 2;
    float2 v = *(const float2*)p;  // c=0,1 contiguous, 8B-aligned
    pair = ((unsigned int)(unsigned short)f2bf(v.x)) |
           (((unsigned int)(unsigned short)f2bf(v.y)) << 16);
  }
  *(unsigned int*)&hA[rem * 224 + kp2 * 2] = pair;
}

// ---- k1[64][200][1024] f32 -> k1t[64][1024][224] bf16 (B^T, zero-padded) -----
__global__ __launch_bounds__(256) void transpose_k1(const float* __restrict__ k1,
                                                    short* __restrict__ k1t) {
  const int j1 = blockIdx.x;          // 64
  const int nBase = blockIdx.y * 64;  // 16
  const int kBase = blockIdx.z * 56;  // 4
  __shared__ short tr[64][68];        // stride 136 B: 8B-aligned, 4-way-max banks
  const int t = threadIdx.x;
  const int nl = t & 63;
  const int ksub = t >> 6;
  const float* src = k1 + (size_t)j1 * 204800 + (size_t)kBase * 1024 + nBase + nl;
#pragma unroll
  for (int pass = 0; pass < 14; ++pass) {
    int kloc = pass * 4 + ksub;
    int k = kBase + kloc;
    tr[nl][kloc] = (k < 200) ? f2bf(src[kloc * 1024]) : (short)0;
  }
  __syncthreads();
  short* dstbase = k1t + ((size_t)j1 * 1024 + nBase) * 224 + kBase;
#pragma unroll
  for (int p = 0; p < 4; ++p) {
    int u = p * 256 + t;
    int row = u >> 4;
    int kq = u & 15;
    if (kq < 14) {
      bfx4 v = *(const bfx4*)&tr[row][kq * 4];
      *(bfx4*)&dstbase[row * 224 + kq * 4] = v;
    }
  }
}

// ---- k3[64][1024][200] f32 -> k3t[64][256][1024] bf16 (B^T, N padded) --------
__global__ __launch_bounds__(256) void transpose_k3(const float* __restrict__ k3,
                                                    short* __restrict__ k3t) {
  const int j3 = blockIdx.x;           // 64
  const int kBase = blockIdx.y * 128;  // 8
  const int nBase = blockIdx.z * 64;   // 4
  __shared__ short tr[64][132];
  const int t = threadIdx.x;
  const int nl = t & 63;
  const int ksub = t >> 6;
  const int nGlob = nBase + nl;
  const bool valid = (nGlob < 200);
  const float* src = k3 + (size_t)j3 * 204800 + (size_t)kBase * 200 + nGlob;
#pragma unroll 4
  for (int pass = 0; pass < 32; ++pass) {
    int k = pass * 4 + ksub;
    tr[nl][k] = valid ? f2bf(src[k * 200]) : (short)0;
  }
  __syncthreads();
  short* dstbase = k3t + ((size_t)j3 * 256 + nBase) * 1024 + kBase;
#pragma unroll
  for (int pass = 0; pass < 8; ++pass) {
    int idx = (pass * 256 + t) * 4;
    int row = idx >> 7;
    int koff = idx & 127;
    bfx4 v = *(const bfx4*)&tr[row][koff];
    *(bfx4*)&dstbase[row * 1024 + koff] = v;
  }
}

// ---- stage 1: per j1, C[BC,1024] = A[BC,224] @ Bt[1024,224]^T + b1 -----------
// v3: port of the stage3-v3 recipe (proven round 2): BK=64 main loop (3 iters,
// XOR-swizzled, conflict-free) + BK=32 linear tail (1 iter), 4 barrier pairs
// instead of 7. XCD-bijective block swizzle (nwg=1024, %8==0).
__global__ __launch_bounds__(256) void gemm_stage1(const short* __restrict__ hA,
                                                   const short* __restrict__ k1t,
                                                   const float* __restrict__ b1,
                                                   short* __restrict__ h1) {
  // grid = (8, 2, 64) -> 1024 blocks. linear id = x + 8y + 16z.
  int bid = (int)blockIdx.x + 8 * (int)blockIdx.y + 16 * (int)blockIdx.z;
  bid = ((bid & 7) << 7) | (bid >> 3);  // bijective: XCD k owns j1 [8k, 8k+8)
  const int nBase = (bid & 7) * 128;
  const int mBase = ((bid >> 3) & 1) * 128;
  const int j1 = bid >> 4;
  __shared__ short As[128 * 64];  // 16 KB, swizzled content in main iters
  __shared__ short Bs[128 * 64];
  const int tid = threadIdx.x;
  const int lane = tid & 63;
  const int wave = tid >> 6;
  const int quad = lane >> 4;
  const int l16 = lane & 15;
  const int wm = wave >> 1, wn = wave & 1;
  // main staging (BK=64): row = c*32 + (tid>>3), phys slot tid&7 holds logical
  // slot (tid&7)^(row&7); row&7 == (tid>>3)&7 for all c (c*32 keeps low 3 bits).
  const int sRow = tid >> 3;
  const int sCol = ((tid & 7) ^ (sRow & 7)) * 8;
  const short* Aj = hA + (size_t)j1 * BC * 224 + (size_t)(mBase + sRow) * 224 + sCol;
  const short* Bj =
      k1t + (size_t)j1 * 1024 * 224 + (size_t)(nBase + sRow) * 224 + sCol;
  // tail staging (BK=32, linear): row = c*64 + (tid>>2), slot tid&3.
  const int tRow = tid >> 2;
  const int tCol = (tid & 3) * 8;
  const short* Ajt =
      hA + (size_t)j1 * BC * 224 + (size_t)(mBase + tRow) * 224 + 192 + tCol;
  const short* Bjt =
      k1t + (size_t)j1 * 1024 * 224 + (size_t)(nBase + tRow) * 224 + 192 + tCol;
  short* ldsA = &As[tid * 8];
  short* ldsB = &Bs[tid * 8];
  floatx4 acc[4][4] = {};

  for (int kk = 0; kk < 192; kk += 64) {
    __syncthreads();
#pragma unroll
    for (int c = 0; c < 4; ++c) {
      gl_lds16(Aj + c * 32 * 224 + kk, ldsA + c * 2048);
      gl_lds16(Bj + c * 32 * 224 + kk, ldsB + c * 2048);
    }
    __syncthreads();
#pragma unroll
    for (int ks = 0; ks < 2; ++ks) {
      short8 af[4], bfv[4];
#pragma unroll
      for (int mt = 0; mt < 4; ++mt) {
        int r = wm * 64 + mt * 16 + l16;
        af[mt] = *(const short8*)&As[r * 64 + ((ks * 4 + quad) ^ (l16 & 7)) * 8];
      }
#pragma unroll
      for (int nt = 0; nt < 4; ++nt) {
        int r = wn * 64 + nt * 16 + l16;
        bfv[nt] = *(const short8*)&Bs[r * 64 + ((ks * 4 + quad) ^ (l16 & 7)) * 8];
      }
#pragma unroll
      for (int mt = 0; mt < 4; ++mt)
#pragma unroll
        for (int nt = 0; nt < 4; ++nt)
          acc[mt][nt] = __builtin_amdgcn_mfma_f32_16x16x32_bf16(af[mt], bfv[nt],
                                                                acc[mt][nt], 0, 0, 0);
    }
  }
  // tail: K [192,224), linear [128][32] layout reusing the same buffers.
  __syncthreads();
  gl_lds16(Ajt, ldsA);
  gl_lds16(Ajt + 64 * 224, ldsA + 2048);
  gl_lds16(Bjt, ldsB);
  gl_lds16(Bjt + 64 * 224, ldsB + 2048);
  __syncthreads();
  {
    short8 af[4], bfv[4];
#pragma unroll
    for (int mt = 0; mt < 4; ++mt)
      af[mt] = *(const short8*)&As[(wm * 64 + mt * 16 + l16) * 32 + quad * 8];
#pragma unroll
    for (int nt = 0; nt < 4; ++nt)
      bfv[nt] = *(const short8*)&Bs[(wn * 64 + nt * 16 + l16) * 32 + quad * 8];
#pragma unroll
    for (int mt = 0; mt < 4; ++mt)
#pragma unroll
      for (int nt = 0; nt < 4; ++nt)
        acc[mt][nt] = __builtin_amdgcn_mfma_f32_16x16x32_bf16(af[mt], bfv[nt],
                                                              acc[mt][nt], 0, 0, 0);
  }
#pragma unroll
  for (int nt = 0; nt < 4; ++nt) {
    int n = nBase + wn * 64 + nt * 16 + l16;
    float bias = b1[j1 * 1024 + n];
#pragma unroll
    for (int mt = 0; mt < 4; ++mt) {
#pragma unroll
      for (int r = 0; r < 4; ++r) {
        int m = mBase + wm * 64 + mt * 16 + quad * 4 + r;
        h1[((size_t)j1 * BC + m) * 1024 + n] = f2bf(acc[mt][nt][r] + bias);
      }
    }
  }
}

// ---- stage 2: permute + tiny GEMMs, h1[64][BC][1024] -> h2p[64][mTot][1024] --
__global__ __launch_bounds__(256) void stage2(const short* __restrict__ h1,
                                              const float* __restrict__ k2,
                                              const float* __restrict__ b2,
                                              short* __restrict__ h2p, int mTot,
                                              int bOff2) {
  const int j1 = blockIdx.x;
  const int bBase = blockIdx.y * 8;
  __shared__ short in_s[8][1024];
  __shared__ short w_s[256 * 66];
  __shared__ float bias_s[16 * 64];
  const int tid = threadIdx.x;
#pragma unroll
  for (int ii = 0; ii < 4; ++ii) {
    int flat = (ii * 256 + tid) * 8;
    int b_loc = flat >> 10;
    int k = flat & 1023;
    *(short8*)&in_s[b_loc][k] =
        *(const short8*)&h1[((size_t)j1 * BC + bBase + b_loc) * 1024 + k];
  }
#pragma unroll
  for (int ii = 0; ii < 16; ++ii) {
    int flat = (ii * 256 + tid) * 4;
    int blk = flat >> 8;
    int within = flat & 255;
    int r = blk >> 2, b2hi = blk & 3;
    int j2 = r * 256 + j1 * 4 + b2hi;
    floatx4 v = *(const floatx4*)&k2[(size_t)j2 * 256 + within];
#pragma unroll
    for (int i = 0; i < 4; ++i) w_s[(within + i) * 66 + blk] = f2bf(v[i]);
  }
  {
    int blk = tid >> 2;
    int r2o = (tid & 3) * 4;
    int r = blk >> 2, b2hi = blk & 3;
    int j2 = r * 256 + j1 * 4 + b2hi;
#pragma unroll
    for (int i = 0; i < 4; ++i) bias_s[(r2o + i) * 64 + blk] = b2[j2 * 16 + r2o + i];
  }
  __syncthreads();
#pragma unroll
  for (int i4 = 0; i4 < 2; ++i4) {
    int idx = i4 * 256 + tid;
    int b_loc = idx >> 6;
    int rem = idx & 63;
    int r = rem >> 2;
    int b2hi = rem & 3;
    float acc[16];
#pragma unroll
    for (int r2 = 0; r2 < 16; ++r2) acc[r2] = bias_s[r2 * 64 + rem];
#pragma unroll
    for (int k = 0; k < 16; ++k) {
      float iv = bf2f(in_s[b_loc][(b2hi * 16 + k) * 16 + r]);
#pragma unroll
      for (int r2 = 0; r2 < 16; ++r2)
        acc[r2] += iv * bf2f(w_s[(k * 16 + r2) * 66 + rem]);
    }
    int j3 = r * 4 + (j1 >> 4);
    int k3o = (j1 & 15) * 64 + b2hi * 16;
    short8 o0, o1;
#pragma unroll
    for (int t = 0; t < 8; ++t) {
      o0[t] = f2bf(acc[t]);
      o1[t] = f2bf(acc[8 + t]);
    }
    short* dst = h2p + ((size_t)j3 * mTot + bOff2 + bBase + b_loc) * 1024 + k3o;
    *(short8*)&dst[0] = o0;
    *(short8*)&dst[8] = o1;
  }
}

// ---- stage 3: per j3, [M,1024] @ k3t^T (+b3), scatter to out f32 -------------
// v3 (round-2 verbatim, verified): 2-barrier, BK=64, XOR swizzle, XCD swizzle.
__global__ __launch_bounds__(256) void gemm_stage3(const short* __restrict__ h2p,
                                                   const short* __restrict__ k3t,
                                                   const float* __restrict__ b3,
                                                   float* __restrict__ out, int mTot,
                                                   int bOffset) {
  // grid = (2, mTot/128, 64); nwg % 8 == 0, swizzle is bijective.
  const int gy = (int)gridDim.y;
  int bid = (int)blockIdx.x + 2 * ((int)blockIdx.y + gy * (int)blockIdx.z);
  const int cpx = (gy << 4);  // nwg/8
  bid = (bid & 7) * cpx + (bid >> 3);
  const int nBase = (bid & 1) * 128;
  const int rest = bid >> 1;
  const int mBase = (rest & (gy - 1)) * 128;
  const int j3 = rest / gy;
  __shared__ short As[128 * 64];  // 16 KB, swizzled content
  __shared__ short Bs[128 * 64];  // 16 KB
  const int tid = threadIdx.x;
  const int lane = tid & 63;
  const int wave = tid >> 6;
  const int quad = lane >> 4;
  const int l16 = lane & 15;
  const int wm = wave >> 1, wn = wave & 1;
  // staging: call c covers rows [c*32, c*32+32); thread -> row = c*32 + (tid>>3),
  // phys 16B-slot = tid&7 which must hold logical slot (tid&7)^(row&7).
  const int sRow = tid >> 3;
  const int sCol = ((tid & 7) ^ (sRow & 7)) * 8;  // shorts; row&7 == sRow&7 for all c
  const short* Aj =
      h2p + (size_t)j3 * mTot * 1024 + (size_t)(mBase + sRow) * 1024 + sCol;
  const short* Bj =
      k3t + (size_t)j3 * 256 * 1024 + (size_t)(nBase + sRow) * 1024 + sCol;
  short* ldsA = &As[tid * 8];
  short* ldsB = &Bs[tid * 8];
  floatx4 acc[4][4] = {};

  for (int kk = 0; kk < 1024; kk += 64) {
    __syncthreads();
#pragma unroll
    for (int c = 0; c < 4; ++c) {
      gl_lds16(Aj + c * 32 * 1024 + kk, ldsA + c * 2048);
      gl_lds16(Bj + c * 32 * 1024 + kk, ldsB + c * 2048);
    }
    __syncthreads();
#pragma unroll
    for (int ks = 0; ks < 2; ++ks) {
      short8 af[4], bfv[4];
#pragma unroll
      for (int mt = 0; mt < 4; ++mt) {
        int r = wm * 64 + mt * 16 + l16;
        af[mt] = *(const short8*)&As[r * 64 + ((ks * 4 + quad) ^ (l16 & 7)) * 8];
      }
#pragma unroll
      for (int nt = 0; nt < 4; ++nt) {
        int r = wn * 64 + nt * 16 + l16;
        bfv[nt] = *(const short8*)&Bs[r * 64 + ((ks * 4 + quad) ^ (l16 & 7)) * 8];
      }
#pragma unroll
      for (int mt = 0; mt < 4; ++mt)
#pragma unroll
        for (int nt = 0; nt < 4; ++nt)
          acc[mt][nt] = __builtin_amdgcn_mfma_f32_16x16x32_bf16(af[mt], bfv[nt],
                                                                acc[mt][nt], 0, 0, 0);
    }
  }
  const int B2x = j3 >> 3, B2y = j3 & 7;
#pragma unroll
  for (int nt = 0; nt < 4; ++nt) {
    int n = nBase + wn * 64 + nt * 16 + l16;
    if (n < 200) {
      float bias = b3[j3 * 200 + n];
      int c = n & 1;
      int t = n >> 1;
      int w2x = t / 10, w2y = t - w2x * 10;
      int orow = B2x * 10 + w2x, ocol = B2y * 10 + w2y;
#pragma unroll
      for (int mt = 0; mt < 4; ++mt) {
#pragma unroll
        for (int r = 0; r < 4; ++r) {
          int m = bOffset + mBase + wm * 64 + mt * 16 + quad * 4 + r;
          out[(((size_t)m * 80 + orow) * 80 + ocol) * 2 + c] = acc[mt][nt][r] + bias;
        }
      }
    }
  }
}

extern "C" void kernel_launch(void* const* d_in, const int* in_sizes, int n_in,
                              void* d_out, int out_size, void* d_ws, size_t ws_size,
                              hipStream_t stream) {
  const float* x = (const float*)d_in[0];
  const float* k1 = (const float*)d_in[1];
  const float* b1 = (const float*)d_in[2];
  const float* k2 = (const float*)d_in[3];
  const float* b2 = (const float*)d_in[4];
  const float* k3 = (const float*)d_in[5];
  const float* b3 = (const float*)d_in[6];
  float* out = (float*)d_out;
  char* ws = (char*)d_ws;

  short* k1t = (short*)(ws);                // 29,360,128
  short* k3t = (short*)(ws + 29360128);     // 33,554,432
  short* hA = (short*)(ws + 62914560);      //  7,340,032
  short* h1c = (short*)(ws + 70254592);     // 33,554,432
  short* h2p = (short*)(ws + 103809024);    // 33,554,432 (chunked) / 134,217,728 (full)

  const bool full = (ws_size >= 238026752ull);  // full h2p fits
  const int mTot = full ? 1024 : BC;

  transpose_k1<<<dim3(64, 16, 4), 256, 0, stream>>>(k1, k1t);
  transpose_k3<<<dim3(64, 8, 4), 256, 0, stream>>>(k3, k3t);
  for (int c = 0; c < 1024 / BC; ++c) {
    int bOffset = c * BC;
    gather_x<<<(64 * BC * 112) / 256, 256, 0, stream>>>(x, hA, bOffset);
    gemm_stage1<<<dim3(8, BC / 128, 64), 256, 0, stream>>>(hA, k1t, b1, h1c);
    stage2<<<dim3(64, BC / 8), 256, 0, stream>>>(h1c, k2, b2, h2p, mTot,
                                                 full ? bOffset : 0);
    if (!full)
      gemm_stage3<<<dim3(2, BC / 128, 64), 256, 0, stream>>>(h2p, k3t, b3, out, BC,
                                                             bOffset);
  }
  if (full)
    gemm_stage3<<<dim3(2, 1024 / 128, 64), 256, 0, stream>>>(h2p, k3t, b3, out, 1024,
                                                             0);
}

// Round 4
// 476.395 us; speedup vs baseline: 1.2473x; 1.1214x over previous
//
#include <hip/hip_runtime.h>

typedef __attribute__((ext_vector_type(8))) short short8;
typedef __attribute__((ext_vector_type(4))) short bfx4;
typedef __attribute__((ext_vector_type(4))) float floatx4;

__device__ __forceinline__ float bf2f(short u) {
  unsigned int i = ((unsigned int)(unsigned short)u) << 16;
  return __builtin_bit_cast(float, i);
}
__device__ __forceinline__ short f2bf(float f) {
  unsigned int x = __builtin_bit_cast(unsigned int, f);
  x += 0x7fffu + ((x >> 16) & 1u);
  return (short)(x >> 16);
}

// async global->LDS, 16B per lane. LDS dest = wave-uniform base + lane*16.
__device__ __forceinline__ void gl_lds16(const short* g, short* lds) {
  __builtin_amdgcn_global_load_lds(
      (const __attribute__((address_space(1))) unsigned int*)g,
      (__attribute__((address_space(3))) unsigned int*)lds, 16, 0, 0);
}

#define BC 256  // batch chunk

// ---- gather: x[B,6400,2] f32 -> hA[64][BC][224] bf16 (K padded 200->224) -----
// v3: one c-pair per thread (float2 load, packed 4B store).
__global__ __launch_bounds__(256) void gather_x(const float* __restrict__ x,
                                                short* __restrict__ hA, int bOffset) {
  int tid = blockIdx.x * 256 + threadIdx.x;
  const int total = 64 * BC * 112;
  if (tid >= total) return;
  int kp2 = tid % 112;   // pair index: w = kp2, covers kp = 2*kp2, 2*kp2+1
  int rem = tid / 112;
  int b_loc = rem & (BC - 1);
  int j1 = rem / BC;
  unsigned int pair = 0;
  if (kp2 < 100) {
    int wx = kp2 / 10;
    int wy = kp2 - wx * 10;
    int bx = j1 >> 3, by = j1 & 7;
    const float* p = x + (size_t)(bOffset + b_loc) * 12800 +
                     ((size_t)(bx * 800 + wx * 80 + by * 10 + wy)) * 2;
    float2 v = *(const float2*)p;  // c=0,1 contiguous, 8B-aligned
    pair = ((unsigned int)(unsigned short)f2bf(v.x)) |
           (((unsigned int)(unsigned short)f2bf(v.y)) << 16);
  }
  *(unsigned int*)&hA[rem * 224 + kp2 * 2] = pair;
}

// ---- k1[64][200][1024] f32 -> k1t[64][1024][224] bf16 (B^T, zero-padded) -----
__global__ __launch_bounds__(256) void transpose_k1(const float* __restrict__ k1,
                                                    short* __restrict__ k1t) {
  const int j1 = blockIdx.x;          // 64
  const int nBase = blockIdx.y * 64;  // 16
  const int kBase = blockIdx.z * 56;  // 4
  __shared__ short tr[64][68];        // stride 136 B: 8B-aligned, 4-way-max banks
  const int t = threadIdx.x;
  const int nl = t & 63;
  const int ksub = t >> 6;
  const float* src = k1 + (size_t)j1 * 204800 + (size_t)kBase * 1024 + nBase + nl;
#pragma unroll
  for (int pass = 0; pass < 14; ++pass) {
    int kloc = pass * 4 + ksub;
    int k = kBase + kloc;
    tr[nl][kloc] = (k < 200) ? f2bf(src[kloc * 1024]) : (short)0;
  }
  __syncthreads();
  short* dstbase = k1t + ((size_t)j1 * 1024 + nBase) * 224 + kBase;
#pragma unroll
  for (int p = 0; p < 4; ++p) {
    int u = p * 256 + t;
    int row = u >> 4;
    int kq = u & 15;
    if (kq < 14) {
      bfx4 v = *(const bfx4*)&tr[row][kq * 4];
      *(bfx4*)&dstbase[row * 224 + kq * 4] = v;
    }
  }
}

// ---- k3[64][1024][200] f32 -> k3t[64][256][1024] bf16 (B^T, N padded) --------
__global__ __launch_bounds__(256) void transpose_k3(const float* __restrict__ k3,
                                                    short* __restrict__ k3t) {
  const int j3 = blockIdx.x;           // 64
  const int kBase = blockIdx.y * 128;  // 8
  const int nBase = blockIdx.z * 64;   // 4
  __shared__ short tr[64][132];
  const int t = threadIdx.x;
  const int nl = t & 63;
  const int ksub = t >> 6;
  const int nGlob = nBase + nl;
  const bool valid = (nGlob < 200);
  const float* src = k3 + (size_t)j3 * 204800 + (size_t)kBase * 200 + nGlob;
#pragma unroll 4
  for (int pass = 0; pass < 32; ++pass) {
    int k = pass * 4 + ksub;
    tr[nl][k] = valid ? f2bf(src[k * 200]) : (short)0;
  }
  __syncthreads();
  short* dstbase = k3t + ((size_t)j3 * 256 + nBase) * 1024 + kBase;
#pragma unroll
  for (int pass = 0; pass < 8; ++pass) {
    int idx = (pass * 256 + t) * 4;
    int row = idx >> 7;
    int koff = idx & 127;
    bfx4 v = *(const bfx4*)&tr[row][koff];
    *(bfx4*)&dstbase[row * 1024 + koff] = v;
  }
}

// ---- stage 1: per j1, C[BC,1024] = A[BC,224] @ Bt[1024,224]^T + b1 -----------
// v3 (round-3 verbatim, verified): BK=64 main loop XOR-swizzled + BK=32 tail,
// XCD-bijective block swizzle.
__global__ __launch_bounds__(256) void gemm_stage1(const short* __restrict__ hA,
                                                   const short* __restrict__ k1t,
                                                   const float* __restrict__ b1,
                                                   short* __restrict__ h1) {
  // grid = (8, 2, 64) -> 1024 blocks. linear id = x + 8y + 16z.
  int bid = (int)blockIdx.x + 8 * (int)blockIdx.y + 16 * (int)blockIdx.z;
  bid = ((bid & 7) << 7) | (bid >> 3);  // bijective: XCD k owns j1 [8k, 8k+8)
  const int nBase = (bid & 7) * 128;
  const int mBase = ((bid >> 3) & 1) * 128;
  const int j1 = bid >> 4;
  __shared__ short As[128 * 64];  // 16 KB, swizzled content in main iters
  __shared__ short Bs[128 * 64];
  const int tid = threadIdx.x;
  const int lane = tid & 63;
  const int wave = tid >> 6;
  const int quad = lane >> 4;
  const int l16 = lane & 15;
  const int wm = wave >> 1, wn = wave & 1;
  // main staging (BK=64): row = c*32 + (tid>>3), phys slot tid&7 holds logical
  // slot (tid&7)^(row&7); row&7 == (tid>>3)&7 for all c (c*32 keeps low 3 bits).
  const int sRow = tid >> 3;
  const int sCol = ((tid & 7) ^ (sRow & 7)) * 8;
  const short* Aj = hA + (size_t)j1 * BC * 224 + (size_t)(mBase + sRow) * 224 + sCol;
  const short* Bj =
      k1t + (size_t)j1 * 1024 * 224 + (size_t)(nBase + sRow) * 224 + sCol;
  // tail staging (BK=32, linear): row = c*64 + (tid>>2), slot tid&3.
  const int tRow = tid >> 2;
  const int tCol = (tid & 3) * 8;
  const short* Ajt =
      hA + (size_t)j1 * BC * 224 + (size_t)(mBase + tRow) * 224 + 192 + tCol;
  const short* Bjt =
      k1t + (size_t)j1 * 1024 * 224 + (size_t)(nBase + tRow) * 224 + 192 + tCol;
  short* ldsA = &As[tid * 8];
  short* ldsB = &Bs[tid * 8];
  floatx4 acc[4][4] = {};

  for (int kk = 0; kk < 192; kk += 64) {
    __syncthreads();
#pragma unroll
    for (int c = 0; c < 4; ++c) {
      gl_lds16(Aj + c * 32 * 224 + kk, ldsA + c * 2048);
      gl_lds16(Bj + c * 32 * 224 + kk, ldsB + c * 2048);
    }
    __syncthreads();
#pragma unroll
    for (int ks = 0; ks < 2; ++ks) {
      short8 af[4], bfv[4];
#pragma unroll
      for (int mt = 0; mt < 4; ++mt) {
        int r = wm * 64 + mt * 16 + l16;
        af[mt] = *(const short8*)&As[r * 64 + ((ks * 4 + quad) ^ (l16 & 7)) * 8];
      }
#pragma unroll
      for (int nt = 0; nt < 4; ++nt) {
        int r = wn * 64 + nt * 16 + l16;
        bfv[nt] = *(const short8*)&Bs[r * 64 + ((ks * 4 + quad) ^ (l16 & 7)) * 8];
      }
#pragma unroll
      for (int mt = 0; mt < 4; ++mt)
#pragma unroll
        for (int nt = 0; nt < 4; ++nt)
          acc[mt][nt] = __builtin_amdgcn_mfma_f32_16x16x32_bf16(af[mt], bfv[nt],
                                                                acc[mt][nt], 0, 0, 0);
    }
  }
  // tail: K [192,224), linear [128][32] layout reusing the same buffers.
  __syncthreads();
  gl_lds16(Ajt, ldsA);
  gl_lds16(Ajt + 64 * 224, ldsA + 2048);
  gl_lds16(Bjt, ldsB);
  gl_lds16(Bjt + 64 * 224, ldsB + 2048);
  __syncthreads();
  {
    short8 af[4], bfv[4];
#pragma unroll
    for (int mt = 0; mt < 4; ++mt)
      af[mt] = *(const short8*)&As[(wm * 64 + mt * 16 + l16) * 32 + quad * 8];
#pragma unroll
    for (int nt = 0; nt < 4; ++nt)
      bfv[nt] = *(const short8*)&Bs[(wn * 64 + nt * 16 + l16) * 32 + quad * 8];
#pragma unroll
    for (int mt = 0; mt < 4; ++mt)
#pragma unroll
      for (int nt = 0; nt < 4; ++nt)
        acc[mt][nt] = __builtin_amdgcn_mfma_f32_16x16x32_bf16(af[mt], bfv[nt],
                                                              acc[mt][nt], 0, 0, 0);
  }
#pragma unroll
  for (int nt = 0; nt < 4; ++nt) {
    int n = nBase + wn * 64 + nt * 16 + l16;
    float bias = b1[j1 * 1024 + n];
#pragma unroll
    for (int mt = 0; mt < 4; ++mt) {
#pragma unroll
      for (int r = 0; r < 4; ++r) {
        int m = mBase + wm * 64 + mt * 16 + quad * 4 + r;
        h1[((size_t)j1 * BC + m) * 1024 + n] = f2bf(acc[mt][nt][r] + bias);
      }
    }
  }
}

// ---- stage 2: permute + tiny GEMMs, h1[64][BC][1024] -> h2p[64][mTot][1024] --
// v4: LDS-instruction-bound fix. Thread owns 8 batch x 8 r2 for a fixed j2
// (acc[8][8]); per k: 8 scalar in-reads + ONE ds_read_b128 of w -> 9 LDS ops
// per 64 FMAs (was 17 per 16). w staged as [k][g][j2part][8] with contiguous
// ds_write_b128 (conflict-free); in_s staged linear via gl_lds16 (async).
// Bias read direct from global (b2 L2-hot). XCD-bijective block swizzle.
__global__ __launch_bounds__(256) void stage2(const short* __restrict__ h1,
                                              const float* __restrict__ k2,
                                              const float* __restrict__ b2,
                                              short* __restrict__ h2p, int mTot,
                                              int bOff2) {
  // grid (64, 16) = 1024 blocks; swizzle: XCD x owns j1 in [8x, 8x+8).
  int bid = (int)blockIdx.x + 64 * (int)blockIdx.y;
  bid = ((bid & 7) << 7) | (bid >> 3);
  const int j1 = bid >> 4;
  const int bBase = (bid & 15) * 16;
  __shared__ short in_s[16 * 1024];  // 32 KB: h1 rows [bBase, bBase+16)
  __shared__ short w_s[16 * 1024];   // 32 KB: [k(16)][g(2)][j2part(64)][8]
  const int tid = threadIdx.x;

  // stage in_s: 16 contiguous h1 rows, linear async copy.
  const short* inSrc = h1 + ((size_t)j1 * BC + bBase) * 1024 + tid * 8;
  short* inDst = &in_s[tid * 8];
#pragma unroll
  for (int c = 0; c < 8; ++c) gl_lds16(inSrc + c * 2048, inDst + c * 2048);

  // stage w_s: gather-convert from k2, LDS-contiguous b128 stores.
#pragma unroll
  for (int p = 0; p < 8; ++p) {
    int idx = p * 256 + tid;               // short8 unit
    int rm = idx & 63;                     // j2-part (r, b2hi)
    int g = (idx >> 6) & 1;                // r2 octet
    int k = idx >> 7;                      // 0..15
    int j2s = (rm >> 2) * 256 + j1 * 4 + (rm & 3);
    const float* s = &k2[(size_t)j2s * 256 + k * 16 + g * 8];
    floatx4 v0 = *(const floatx4*)s;
    floatx4 v1 = *(const floatx4*)(s + 4);
    short8 w;
#pragma unroll
    for (int i = 0; i < 4; ++i) {
      w[i] = f2bf(v0[i]);
      w[4 + i] = f2bf(v1[i]);
    }
    *(short8*)&w_s[idx * 8] = w;
  }
  __syncthreads();

  const int rem = tid & 63;   // j2-part
  const int oct = tid >> 6;   // wave
  const int bh = oct & 1;     // batch half (8 rows)
  const int ro = oct >> 1;    // r2 octet
  const int r = rem >> 2, b2hi = rem & 3;
  const int j2 = r * 256 + j1 * 4 + b2hi;

  float acc[8][8];
  {
    const float* bb = &b2[(size_t)j2 * 16 + ro * 8];
    floatx4 bz0 = *(const floatx4*)bb;
    floatx4 bz1 = *(const floatx4*)(bb + 4);
#pragma unroll
    for (int b = 0; b < 8; ++b)
#pragma unroll
      for (int j = 0; j < 4; ++j) {
        acc[b][j] = bz0[j];
        acc[b][4 + j] = bz1[j];
      }
  }
  const short* inb = &in_s[(bh * 8) * 1024 + (b2hi * 16) * 16 + r];
  const short* wb = &w_s[(ro * 64 + rem) * 8];
#pragma unroll
  for (int k = 0; k < 16; ++k) {
    short8 w8 = *(const short8*)&wb[k * 1024];  // [k][ro][rem][0..8)
    float wf[8];
#pragma unroll
    for (int j = 0; j < 8; ++j) wf[j] = bf2f(w8[j]);
#pragma unroll
    for (int b = 0; b < 8; ++b) {
      float iv = bf2f(inb[b * 1024 + k * 16]);
#pragma unroll
      for (int j = 0; j < 8; ++j) acc[b][j] += iv * wf[j];
    }
  }
  const int j3 = r * 4 + (j1 >> 4);
  const int k3o = (j1 & 15) * 64 + b2hi * 16 + ro * 8;
#pragma unroll
  for (int b = 0; b < 8; ++b) {
    short8 o;
#pragma unroll
    for (int j = 0; j < 8; ++j) o[j] = f2bf(acc[b][j]);
    short* dst =
        h2p + ((size_t)j3 * mTot + bOff2 + bBase + bh * 8 + b) * 1024 + k3o;
    *(short8*)dst = o;
  }
}

// ---- stage 3: per j3, [M,1024] @ k3t^T (+b3), scatter to out f32 -------------
// v3 (round-2 verbatim, verified): 2-barrier, BK=64, XOR swizzle, XCD swizzle.
__global__ __launch_bounds__(256) void gemm_stage3(const short* __restrict__ h2p,
                                                   const short* __restrict__ k3t,
                                                   const float* __restrict__ b3,
                                                   float* __restrict__ out, int mTot,
                                                   int bOffset) {
  // grid = (2, mTot/128, 64); nwg % 8 == 0, swizzle is bijective.
  const int gy = (int)gridDim.y;
  int bid = (int)blockIdx.x + 2 * ((int)blockIdx.y + gy * (int)blockIdx.z);
  const int cpx = (gy << 4);  // nwg/8
  bid = (bid & 7) * cpx + (bid >> 3);
  const int nBase = (bid & 1) * 128;
  const int rest = bid >> 1;
  const int mBase = (rest & (gy - 1)) * 128;
  const int j3 = rest / gy;
  __shared__ short As[128 * 64];  // 16 KB, swizzled content
  __shared__ short Bs[128 * 64];  // 16 KB
  const int tid = threadIdx.x;
  const int lane = tid & 63;
  const int wave = tid >> 6;
  const int quad = lane >> 4;
  const int l16 = lane & 15;
  const int wm = wave >> 1, wn = wave & 1;
  // staging: call c covers rows [c*32, c*32+32); thread -> row = c*32 + (tid>>3),
  // phys 16B-slot = tid&7 which must hold logical slot (tid&7)^(row&7).
  const int sRow = tid >> 3;
  const int sCol = ((tid & 7) ^ (sRow & 7)) * 8;  // shorts; row&7 == sRow&7 for all c
  const short* Aj =
      h2p + (size_t)j3 * mTot * 1024 + (size_t)(mBase + sRow) * 1024 + sCol;
  const short* Bj =
      k3t + (size_t)j3 * 256 * 1024 + (size_t)(nBase + sRow) * 1024 + sCol;
  short* ldsA = &As[tid * 8];
  short* ldsB = &Bs[tid * 8];
  floatx4 acc[4][4] = {};

  for (int kk = 0; kk < 1024; kk += 64) {
    __syncthreads();
#pragma unroll
    for (int c = 0; c < 4; ++c) {
      gl_lds16(Aj + c * 32 * 1024 + kk, ldsA + c * 2048);
      gl_lds16(Bj + c * 32 * 1024 + kk, ldsB + c * 2048);
    }
    __syncthreads();
#pragma unroll
    for (int ks = 0; ks < 2; ++ks) {
      short8 af[4], bfv[4];
#pragma unroll
      for (int mt = 0; mt < 4; ++mt) {
        int r = wm * 64 + mt * 16 + l16;
        af[mt] = *(const short8*)&As[r * 64 + ((ks * 4 + quad) ^ (l16 & 7)) * 8];
      }
#pragma unroll
      for (int nt = 0; nt < 4; ++nt) {
        int r = wn * 64 + nt * 16 + l16;
        bfv[nt] = *(const short8*)&Bs[r * 64 + ((ks * 4 + quad) ^ (l16 & 7)) * 8];
      }
#pragma unroll
      for (int mt = 0; mt < 4; ++mt)
#pragma unroll
        for (int nt = 0; nt < 4; ++nt)
          acc[mt][nt] = __builtin_amdgcn_mfma_f32_16x16x32_bf16(af[mt], bfv[nt],
                                                                acc[mt][nt], 0, 0, 0);
    }
  }
  const int B2x = j3 >> 3, B2y = j3 & 7;
#pragma unroll
  for (int nt = 0; nt < 4; ++nt) {
    int n = nBase + wn * 64 + nt * 16 + l16;
    if (n < 200) {
      float bias = b3[j3 * 200 + n];
      int c = n & 1;
      int t = n >> 1;
      int w2x = t / 10, w2y = t - w2x * 10;
      int orow = B2x * 10 + w2x, ocol = B2y * 10 + w2y;
#pragma unroll
      for (int mt = 0; mt < 4; ++mt) {
#pragma unroll
        for (int r = 0; r < 4; ++r) {
          int m = bOffset + mBase + wm * 64 + mt * 16 + quad * 4 + r;
          out[(((size_t)m * 80 + orow) * 80 + ocol) * 2 + c] = acc[mt][nt][r] + bias;
        }
      }
    }
  }
}

extern "C" void kernel_launch(void* const* d_in, const int* in_sizes, int n_in,
                              void* d_out, int out_size, void* d_ws, size_t ws_size,
                              hipStream_t stream) {
  const float* x = (const float*)d_in[0];
  const float* k1 = (const float*)d_in[1];
  const float* b1 = (const float*)d_in[2];
  const float* k2 = (const float*)d_in[3];
  const float* b2 = (const float*)d_in[4];
  const float* k3 = (const float*)d_in[5];
  const float* b3 = (const float*)d_in[6];
  float* out = (float*)d_out;
  char* ws = (char*)d_ws;

  short* k1t = (short*)(ws);                // 29,360,128
  short* k3t = (short*)(ws + 29360128);     // 33,554,432
  short* hA = (short*)(ws + 62914560);      //  7,340,032
  short* h1c = (short*)(ws + 70254592);     // 33,554,432
  short* h2p = (short*)(ws + 103809024);    // 33,554,432 (chunked) / 134,217,728 (full)

  const bool full = (ws_size >= 238026752ull);  // full h2p fits
  const int mTot = full ? 1024 : BC;

  transpose_k1<<<dim3(64, 16, 4), 256, 0, stream>>>(k1, k1t);
  transpose_k3<<<dim3(64, 8, 4), 256, 0, stream>>>(k3, k3t);
  for (int c = 0; c < 1024 / BC; ++c) {
    int bOffset = c * BC;
    gather_x<<<(64 * BC * 112) / 256, 256, 0, stream>>>(x, hA, bOffset);
    gemm_stage1<<<dim3(8, BC / 128, 64), 256, 0, stream>>>(hA, k1t, b1, h1c);
    stage2<<<dim3(64, BC / 16), 256, 0, stream>>>(h1c, k2, b2, h2p, mTot,
                                                  full ? bOffset : 0);
    if (!full)
      gemm_stage3<<<dim3(2, BC / 128, 64), 256, 0, stream>>>(h2p, k3t, b3, out, BC,
                                                             bOffset);
  }
  if (full)
    gemm_stage3<<<dim3(2, 1024 / 128, 64), 256, 0, stream>>>(h2p, k3t, b3, out, 1024,
                                                             0);
}